// Round 1
// baseline (2060.824 us; speedup 1.0000x reference)
//
#include <hip/hip_runtime.h>

typedef unsigned short u16;

#define NPAPER  100000
#define NAUTHOR 100000
#define NFIELD  50000
#define FIN     128
#define OUTF    349

#define E_WR 1000000
#define E_RW 1000000
#define E_CI 2000000
#define E_HT 1000000
#define E_RH 1000000
#define E_TOT 6000000

// col-space (edge) offsets, concat order: wr, ci, rh, rw, ht
#define CO_CI 1000000
#define CO_RH 3000000
#define CO_RW 4000000
#define CO_HT 5000000
// deg/node-space offsets
#define DB_WR 0
#define DB_CI 100000
#define DB_RH 200000
#define DB_RW 300000
#define DB_HT 400000
#define NDEG  450000

static __device__ __forceinline__ float bf2f(u16 u) {
  union { unsigned int i; float f; } c; c.i = ((unsigned int)u) << 16; return c.f;
}
static __device__ __forceinline__ u16 f2bf(float f) {
  union { float f; unsigned int i; } c; c.f = f;
  unsigned int r = c.i + 0x7fffu + ((c.i >> 16) & 1u);
  return (u16)(r >> 16);
}

// ---------------- CSR build ----------------
__global__ void count_k(const int* __restrict__ wr, const int* __restrict__ rw,
                        const int* __restrict__ ci, const int* __restrict__ ht,
                        const int* __restrict__ rh, int* __restrict__ deg) {
  int e = blockIdx.x * 256 + threadIdx.x;
  if (e >= E_TOT) return;
  const int* ei; int el, db, E;
  if (e < CO_CI)      { ei = wr; el = e;         db = DB_WR; E = E_WR; }
  else if (e < CO_RH) { ei = ci; el = e - CO_CI; db = DB_CI; E = E_CI; }
  else if (e < CO_RW) { ei = rh; el = e - CO_RH; db = DB_RH; E = E_RH; }
  else if (e < CO_HT) { ei = rw; el = e - CO_RW; db = DB_RW; E = E_RW; }
  else                { ei = ht; el = e - CO_HT; db = DB_HT; E = E_HT; }
  atomicAdd(&deg[db + ei[E + el]], 1);
}

__global__ void fill_k(const int* __restrict__ wr, const int* __restrict__ rw,
                       const int* __restrict__ ci, const int* __restrict__ ht,
                       const int* __restrict__ rh, int* __restrict__ cursor,
                       int* __restrict__ colall) {
  int e = blockIdx.x * 256 + threadIdx.x;
  if (e >= E_TOT) return;
  const int* ei; int el, db, E;
  if (e < CO_CI)      { ei = wr; el = e;         db = DB_WR; E = E_WR; }
  else if (e < CO_RH) { ei = ci; el = e - CO_CI; db = DB_CI; E = E_CI; }
  else if (e < CO_RW) { ei = rh; el = e - CO_RH; db = DB_RH; E = E_RH; }
  else if (e < CO_HT) { ei = rw; el = e - CO_RW; db = DB_RW; E = E_RW; }
  else                { ei = ht; el = e - CO_HT; db = DB_HT; E = E_HT; }
  int src = ei[el];
  int p = atomicAdd(&cursor[db + ei[E + el]], 1);
  colall[p] = src;
}

__global__ void scan1(const int* __restrict__ deg, int* __restrict__ rowptr,
                      int* __restrict__ partials) {
  __shared__ int sh[256];
  int tid = threadIdx.x;
  int base = blockIdx.x * 1024 + tid * 4;
  int v0 = (base + 0 < NDEG) ? deg[base + 0] : 0;
  int v1 = (base + 1 < NDEG) ? deg[base + 1] : 0;
  int v2 = (base + 2 < NDEG) ? deg[base + 2] : 0;
  int v3 = (base + 3 < NDEG) ? deg[base + 3] : 0;
  int s = v0 + v1 + v2 + v3;
  sh[tid] = s; __syncthreads();
  int val = s;
  for (int off = 1; off < 256; off <<= 1) {
    int t = (tid >= off) ? sh[tid - off] : 0;
    __syncthreads();
    val += t; sh[tid] = val;
    __syncthreads();
  }
  int excl = val - s;
  if (base + 0 < NDEG) rowptr[base + 0] = excl;
  if (base + 1 < NDEG) rowptr[base + 1] = excl + v0;
  if (base + 2 < NDEG) rowptr[base + 2] = excl + v0 + v1;
  if (base + 3 < NDEG) rowptr[base + 3] = excl + v0 + v1 + v2;
  if (tid == 255) partials[blockIdx.x] = val;
}

__global__ void scan2(int* partials) {
  __shared__ int sh[512];
  int tid = threadIdx.x;
  int v = (tid < 440) ? partials[tid] : 0;
  sh[tid] = v; __syncthreads();
  int val = v;
  for (int off = 1; off < 512; off <<= 1) {
    int t = (tid >= off) ? sh[tid - off] : 0;
    __syncthreads();
    val += t; sh[tid] = val;
    __syncthreads();
  }
  if (tid < 440) partials[tid] = val - v;
}

__global__ void scan3(int* __restrict__ rowptr, int* __restrict__ cursor,
                      const int* __restrict__ partials) {
  int tid = threadIdx.x;
  int base = blockIdx.x * 1024 + tid * 4;
  int add = partials[blockIdx.x];
#pragma unroll
  for (int j = 0; j < 4; ++j) {
    int idx = base + j;
    if (idx < NDEG) { int val = rowptr[idx] + add; rowptr[idx] = val; cursor[idx] = val; }
  }
  if (blockIdx.x == 0 && tid == 0) rowptr[NDEG] = E_TOT;
}

// ---------------- weight prep ----------------
struct PrepArgs {
  const float *wl1_wr, *wr1_wr, *b1_wr;
  const float *wl1_rw, *wr1_rw, *b1_rw;
  const float *wl1_ci, *wr1_ci, *b1_ci;
  const float *wl1_ht, *wr1_ht, *b1_ht;
  const float *wl1_rh, *wr1_rh, *b1_rh;
  const float *wl2_wr, *wr2_wr, *b2_wr;
  const float *wl2_ci, *wr2_ci, *b2_ci;
  const float *wl2_rh, *wr2_rh, *b2_rh;
  float *Bp, *biasP, *Ba, *biasA, *Bf, *biasF, *B2, *bias2;
};

#define PREP_TOT 155741
__global__ void prep_k(PrepArgs a) {
  int i = blockIdx.x * 256 + threadIdx.x;
  if (i >= PREP_TOT) return;
  if (i < 32768) {                 // Bp 128x256: [ci | rw | ht | sum(wr1_*)]
    int k = i >> 8, c = i & 255;
    float v;
    if (c < 64)       v = a.wl1_ci[k * 64 + c];
    else if (c < 128) v = a.wl1_rw[k * 64 + (c - 64)];
    else if (c < 192) v = a.wl1_ht[k * 64 + (c - 128)];
    else { int cc = c - 192; v = a.wr1_wr[k*64+cc] + a.wr1_ci[k*64+cc] + a.wr1_rh[k*64+cc]; }
    a.Bp[i] = v;
  } else if (i < 49152) {          // Ba 128x128: [wl1_wr | wr1_rw]
    int j = i - 32768; int k = j >> 7, c = j & 127;
    a.Ba[j] = (c < 64) ? a.wl1_wr[k*64 + c] : a.wr1_rw[k*64 + (c - 64)];
  } else if (i < 65536) {          // Bf 128x128: [wl1_rh | wr1_ht]
    int j = i - 49152; int k = j >> 7, c = j & 127;
    a.Bf[j] = (c < 64) ? a.wl1_rh[k*64 + c] : a.wr1_ht[k*64 + (c - 64)];
  } else if (i < 154880) {         // B2 256x349: [wl2_wr; wl2_ci; wl2_rh; sum(wr2_*)]
    int j = i - 65536; int k = j / 349, c = j % 349;
    float v;
    if (k < 64)       v = a.wl2_wr[k * 349 + c];
    else if (k < 128) v = a.wl2_ci[(k - 64) * 349 + c];
    else if (k < 192) v = a.wl2_rh[(k - 128) * 349 + c];
    else { int kk = k - 192; v = a.wr2_wr[kk*349+c] + a.wr2_ci[kk*349+c] + a.wr2_rh[kk*349+c]; }
    a.B2[j] = v;
  } else if (i < 155136) {         // biasP 256
    int c = i - 154880;
    a.biasP[c] = (c < 192) ? 0.f : (a.b1_wr[c-192] + a.b1_ci[c-192] + a.b1_rh[c-192]);
  } else if (i < 155264) {         // biasA 128
    int c = i - 155136;
    a.biasA[c] = (c < 64) ? 0.f : a.b1_rw[c - 64];
  } else if (i < 155392) {         // biasF 128
    int c = i - 155264;
    a.biasF[c] = (c < 64) ? 0.f : a.b1_ht[c - 64];
  } else {                         // bias2 349
    int c = i - 155392;
    a.bias2[c] = a.b2_wr[c] + a.b2_ci[c] + a.b2_rh[c];
  }
}

// ---------------- GEMM (fp32 vector, 64x64 tile, KT=32) ----------------
static __device__ __forceinline__ float ldA1(const float* p) { return *p; }
static __device__ __forceinline__ float ldA1(const u16* p)   { return bf2f(*p); }
static __device__ __forceinline__ void stC(float* p, float v) { *p = v; }
static __device__ __forceinline__ void stC(u16* p, float v)   { *p = f2bf(v); }

template <typename AT, typename CT>
__global__ __launch_bounds__(256) void gemm_kernel(
    const AT* __restrict__ A, const float* __restrict__ B,
    const float* __restrict__ bias, CT* __restrict__ C, int M, int N, int K) {
  __shared__ __align__(16) float As[32][68];
  __shared__ __align__(16) float Bs[32][68];
  int tid = threadIdx.x;
  int tx = tid & 15, ty = tid >> 4;
  int row0 = blockIdx.x * 64, col0 = blockIdx.y * 64;
  float acc[4][4] = {};
  for (int k0 = 0; k0 < K; k0 += 32) {
    __syncthreads();
#pragma unroll
    for (int it = 0; it < 8; ++it) {       // A: 64 rows x 32 k, transposed into As[k][r]
      int idx = tid + it * 256;
      int r = idx >> 5, kk = idx & 31;
      int row = row0 + r;
      float v = 0.f;
      if (row < M) v = ldA1(A + (size_t)row * K + k0 + kk);
      As[kk][r] = v;
    }
#pragma unroll
    for (int it = 0; it < 8; ++it) {       // B: 32 k x 64 cols
      int idx = tid + it * 256;
      int kk = idx >> 6, c = idx & 63;
      int col = col0 + c;
      float v = 0.f;
      if (col < N) v = B[(size_t)(k0 + kk) * N + col];
      Bs[kk][c] = v;
    }
    __syncthreads();
#pragma unroll
    for (int kk = 0; kk < 32; ++kk) {
      float4 av = *(const float4*)&As[kk][ty * 4];
      float4 bv = *(const float4*)&Bs[kk][tx * 4];
      acc[0][0] += av.x * bv.x; acc[0][1] += av.x * bv.y; acc[0][2] += av.x * bv.z; acc[0][3] += av.x * bv.w;
      acc[1][0] += av.y * bv.x; acc[1][1] += av.y * bv.y; acc[1][2] += av.y * bv.z; acc[1][3] += av.y * bv.w;
      acc[2][0] += av.z * bv.x; acc[2][1] += av.z * bv.y; acc[2][2] += av.z * bv.z; acc[2][3] += av.z * bv.w;
      acc[3][0] += av.w * bv.x; acc[3][1] += av.w * bv.y; acc[3][2] += av.w * bv.z; acc[3][3] += av.w * bv.w;
    }
  }
#pragma unroll
  for (int i = 0; i < 4; ++i)
#pragma unroll
    for (int j = 0; j < 4; ++j) {
      int row = row0 + ty * 4 + i, col = col0 + tx * 4 + j;
      if (row < M && col < N) stC(C + (size_t)row * N + col, acc[i][j] + bias[col]);
    }
}

// ---------------- aggregation: one wave per dst node, lane = feature dim ----------------
__global__ __launch_bounds__(256) void agg_kernel(
    const int* __restrict__ rowptr, const int* __restrict__ colall,
    int n_nodes, int n_types, int combine, int do_relu,
    int rpb0, const u16* __restrict__ s0, int st0, int co0,
    int rpb1, const u16* __restrict__ s1, int st1, int co1,
    int rpb2, const u16* __restrict__ s2, int st2, int co2,
    const u16* __restrict__ selfp, int sst, int sco,
    u16* __restrict__ out, int ost, int oco) {
  int lane = threadIdx.x & 63;
  int node = (int)((blockIdx.x * (unsigned)blockDim.x + threadIdx.x) >> 6);
  if (node >= n_nodes) return;
  float tot = 0.f;
  for (int t = 0; t < n_types; ++t) {
    int rpb = (t == 0) ? rpb0 : ((t == 1) ? rpb1 : rpb2);
    const u16* s = (t == 0) ? s0 : ((t == 1) ? s1 : s2);
    int st = (t == 0) ? st0 : ((t == 1) ? st1 : st2);
    int co = (t == 0) ? co0 : ((t == 1) ? co1 : co2);
    int b = rowptr[rpb + node];
    int e = rowptr[rpb + node + 1];
    float acc = 0.f;
    int i = b;
    for (; i + 4 <= e; i += 4) {
      int c0 = colall[i], c1 = colall[i + 1], c2 = colall[i + 2], c3 = colall[i + 3];
      float f0 = bf2f(s[c0 * st + co + lane]);
      float f1 = bf2f(s[c1 * st + co + lane]);
      float f2 = bf2f(s[c2 * st + co + lane]);
      float f3 = bf2f(s[c3 * st + co + lane]);
      acc += (f0 + f1) + (f2 + f3);
    }
    for (; i < e; ++i) acc += bf2f(s[colall[i] * st + co + lane]);
    float m = acc / fmaxf((float)(e - b), 1.f);
    if (combine) tot += m;
    else out[(size_t)node * ost + oco + t * 64 + lane] = f2bf(m);
  }
  if (combine) {
    if (selfp) tot += bf2f(selfp[(size_t)node * sst + sco + lane]);
    if (do_relu) tot = fmaxf(tot, 0.f);
    out[(size_t)node * ost + oco + lane] = f2bf(tot);
  }
}

// ---------------- host ----------------
extern "C" void kernel_launch(void* const* d_in, const int* in_sizes, int n_in,
                              void* d_out, int out_size, void* d_ws, size_t ws_size,
                              hipStream_t stream) {
  (void)in_sizes; (void)n_in; (void)out_size; (void)ws_size;
  const float* x_paper  = (const float*)d_in[0];
  const float* x_author = (const float*)d_in[1];
  const float* x_field  = (const float*)d_in[2];
  const int* ei_wr = (const int*)d_in[3];
  const int* ei_rw = (const int*)d_in[4];
  const int* ei_ci = (const int*)d_in[5];
  const int* ei_ht = (const int*)d_in[6];
  const int* ei_rh = (const int*)d_in[7];
  float* out = (float*)d_out;

  char* w = (char*)d_ws;
  auto alloc = [&](size_t b) { char* p = w; w += (b + 255) & ~(size_t)255; return p; };
  int* deg      = (int*)alloc((size_t)NDEG * 4);
  int* rowptr   = (int*)alloc((size_t)(NDEG + 1) * 4);
  int* cursor   = (int*)alloc((size_t)NDEG * 4);
  int* partials = (int*)alloc(2048 * 4);
  int* colall   = (int*)alloc((size_t)E_TOT * 4);
  // yp cols: [0:64]=ci-proj [64:128]=rw-proj [128:192]=ht-proj [192:256]=self -> p1; later cols 0:192 = L2 means
  u16* yp = (u16*)alloc((size_t)NPAPER * 256 * 2);
  // ya cols: [0:64]=wr-proj -> a1, [64:128]=self
  u16* ya = (u16*)alloc((size_t)NAUTHOR * 128 * 2);
  // yf cols: [0:64]=rh-proj -> f1, [64:128]=self
  u16* yf = (u16*)alloc((size_t)NFIELD * 128 * 2);
  float* Bp    = (float*)alloc(32768 * 4);
  float* biasP = (float*)alloc(256 * 4);
  float* Ba    = (float*)alloc(16384 * 4);
  float* biasA = (float*)alloc(128 * 4);
  float* Bf    = (float*)alloc(16384 * 4);
  float* biasF = (float*)alloc(128 * 4);
  float* B2    = (float*)alloc(89344 * 4);
  float* bias2 = (float*)alloc(352 * 4);

  hipMemsetAsync(deg, 0, (size_t)NDEG * 4, stream);
  count_k<<<(E_TOT + 255) / 256, 256, 0, stream>>>(ei_wr, ei_rw, ei_ci, ei_ht, ei_rh, deg);
  scan1<<<440, 256, 0, stream>>>(deg, rowptr, partials);
  scan2<<<1, 512, 0, stream>>>(partials);
  scan3<<<440, 256, 0, stream>>>(rowptr, cursor, partials);
  fill_k<<<(E_TOT + 255) / 256, 256, 0, stream>>>(ei_wr, ei_rw, ei_ci, ei_ht, ei_rh, cursor, colall);

  PrepArgs pa;
  pa.wl1_wr = (const float*)d_in[8];  pa.wr1_wr = (const float*)d_in[9];  pa.b1_wr = (const float*)d_in[10];
  pa.wl1_rw = (const float*)d_in[11]; pa.wr1_rw = (const float*)d_in[12]; pa.b1_rw = (const float*)d_in[13];
  pa.wl1_ci = (const float*)d_in[14]; pa.wr1_ci = (const float*)d_in[15]; pa.b1_ci = (const float*)d_in[16];
  pa.wl1_ht = (const float*)d_in[17]; pa.wr1_ht = (const float*)d_in[18]; pa.b1_ht = (const float*)d_in[19];
  pa.wl1_rh = (const float*)d_in[20]; pa.wr1_rh = (const float*)d_in[21]; pa.b1_rh = (const float*)d_in[22];
  pa.wl2_wr = (const float*)d_in[23]; pa.wr2_wr = (const float*)d_in[24]; pa.b2_wr = (const float*)d_in[25];
  pa.wl2_ci = (const float*)d_in[26]; pa.wr2_ci = (const float*)d_in[27]; pa.b2_ci = (const float*)d_in[28];
  pa.wl2_rh = (const float*)d_in[29]; pa.wr2_rh = (const float*)d_in[30]; pa.b2_rh = (const float*)d_in[31];
  pa.Bp = Bp; pa.biasP = biasP; pa.Ba = Ba; pa.biasA = biasA;
  pa.Bf = Bf; pa.biasF = biasF; pa.B2 = B2; pa.bias2 = bias2;
  prep_k<<<(PREP_TOT + 255) / 256, 256, 0, stream>>>(pa);

  // layer-1 projections (+ fused self/bias blocks)
  gemm_kernel<float, u16><<<dim3(1563, 4), 256, 0, stream>>>(x_paper,  Bp, biasP, yp, NPAPER,  256, FIN);
  gemm_kernel<float, u16><<<dim3(1563, 2), 256, 0, stream>>>(x_author, Ba, biasA, ya, NAUTHOR, 128, FIN);
  gemm_kernel<float, u16><<<dim3(782, 2),  256, 0, stream>>>(x_field,  Bf, biasF, yf, NFIELD,  128, FIN);

  // layer-1 aggregation: p1 -> yp[:,192:256], a1 -> ya[:,0:64], f1 -> yf[:,0:64]
  agg_kernel<<<25000, 256, 0, stream>>>(rowptr, colall, NPAPER, 3, 1, 1,
      DB_WR, ya, 128, 0, DB_CI, yp, 256, 0, DB_RH, yf, 128, 0,
      yp, 256, 192, yp, 256, 192);
  agg_kernel<<<25000, 256, 0, stream>>>(rowptr, colall, NAUTHOR, 1, 1, 1,
      DB_RW, yp, 256, 64, 0, (const u16*)nullptr, 0, 0, 0, (const u16*)nullptr, 0, 0,
      ya, 128, 64, ya, 128, 0);
  agg_kernel<<<12500, 256, 0, stream>>>(rowptr, colall, NFIELD, 1, 1, 1,
      DB_HT, yp, 256, 128, 0, (const u16*)nullptr, 0, 0, 0, (const u16*)nullptr, 0, 0,
      yf, 128, 64, yf, 128, 0);
  // layer-2 aggregation: means into yp[:,0:192] (reads p1 at yp[:,192:256], a1, f1)
  agg_kernel<<<25000, 256, 0, stream>>>(rowptr, colall, NPAPER, 3, 0, 0,
      DB_WR, ya, 128, 0, DB_CI, yp, 256, 192, DB_RH, yf, 128, 0,
      (const u16*)nullptr, 0, 0, yp, 256, 0);

  // final fused GEMM: [m_wr | m_ci | m_rh | p1] @ B2 + bias2 -> out
  gemm_kernel<u16, float><<<dim3(1563, 6), 256, 0, stream>>>(yp, B2, bias2, out, NPAPER, OUTF, 256);
}